// Round 8
// baseline (285.490 us; speedup 1.0000x reference)
//
#include <hip/hip_runtime.h>
#include <hip/hip_bf16.h>

// Problem constants (MoEAdaptorLayer_111669150283)
#define BATCH   512
#define LSEQ    50
#define DIN     768
#define DOUT    300
#define NEXP    8
#define NTOK    (BATCH * LSEQ)      // 25600

typedef __bf16 bf16_t;
typedef __attribute__((ext_vector_type(8))) __bf16 bf16x8;
typedef __attribute__((ext_vector_type(4))) float f32x4;

// async global->LDS, 16 B per lane, dst = wave-uniform base + lane*16
#define GLDS16(g, l) __builtin_amdgcn_global_load_lds( \
    (__attribute__((address_space(1))) void*)(g), \
    (__attribute__((address_space(3))) void*)(l), 16, 0, 0)

static __device__ __forceinline__ unsigned short f2bf(float f) {
    unsigned u = __float_as_uint(f);
    u = (u + 0x7fff + ((u >> 16) & 1)) >> 16;   // round-to-nearest-even
    return (unsigned short)u;
}

// ---------------------------------------------------------------------------
// Kernel 1 (merged prep): block-range split. VERBATIM R0 (verified, ~33 us).
//   blocks [0, 6400):    xb = bf16(x), gates = softmax(x @ w_gate)
//   blocks [6400, 7600): bw[l,e,o] = <bias[e,l,:], W[e,o,:]>, wb = bf16(W)
// ---------------------------------------------------------------------------
#define PREP_GATE_BLOCKS (NTOK / 4)              // 6400
#define PREP_BW_BLOCKS   ((2 * NEXP * DOUT) / 4) // 1200

__global__ __launch_bounds__(256) void prep_kernel(
    const float* __restrict__ x, const float* __restrict__ wg,
    const float* __restrict__ bias, const float* __restrict__ W,
    unsigned short* __restrict__ xb, float* __restrict__ gates,
    float* __restrict__ bw, unsigned short* __restrict__ wb)
{
    const int tid  = threadIdx.x;
    const int lane = tid & 63;

    if (blockIdx.x < PREP_GATE_BLOCKS) {
        __shared__ float wgT[NEXP][DIN + 4];   // transposed gate weights
        #pragma unroll
        for (int r = 0; r < 6; ++r) {
            int j = tid + 256 * r;             // float4 index 0..1535
            float4 v = ((const float4*)wg)[j];
            int i  = j >> 1;
            int e0 = (j & 1) * 4;
            wgT[e0 + 0][i] = v.x;
            wgT[e0 + 1][i] = v.y;
            wgT[e0 + 2][i] = v.z;
            wgT[e0 + 3][i] = v.w;
        }
        __syncthreads();

        int t = blockIdx.x * 4 + (tid >> 6);
        const float4* xr = (const float4*)(x + (size_t)t * DIN);
        ushort4* xo = (ushort4*)(xb + (size_t)t * DIN);

        float acc[NEXP];
        #pragma unroll
        for (int e = 0; e < NEXP; e++) acc[e] = 0.0f;

        #pragma unroll
        for (int k = 0; k < 3; ++k) {
            int i4 = lane + 64 * k;
            float4 v = xr[i4];
            ushort4 u;
            u.x = f2bf(v.x); u.y = f2bf(v.y); u.z = f2bf(v.z); u.w = f2bf(v.w);
            xo[i4] = u;
            #pragma unroll
            for (int e = 0; e < NEXP; ++e) {
                float4 wv = *(const float4*)&wgT[e][4 * i4];
                acc[e] += v.x * wv.x + v.y * wv.y + v.z * wv.z + v.w * wv.w;
            }
        }
        #pragma unroll
        for (int e = 0; e < NEXP; e++) {
            #pragma unroll
            for (int m = 32; m > 0; m >>= 1) acc[e] += __shfl_xor(acc[e], m, 64);
        }
        float mx = acc[0];
        #pragma unroll
        for (int e = 1; e < NEXP; e++) mx = fmaxf(mx, acc[e]);
        float ex[NEXP]; float s = 0.0f;
        #pragma unroll
        for (int e = 0; e < NEXP; e++) { ex[e] = __expf(acc[e] - mx); s += ex[e]; }
        float inv = 1.0f / s;
        if (lane == 0) {
            #pragma unroll
            for (int e = 0; e < NEXP; e++) gates[(size_t)t * NEXP + e] = ex[e] * inv;
        }
    } else {
        int wid  = (blockIdx.x - PREP_GATE_BLOCKS) * 4 + (tid >> 6);  // 0..4799
        int half = wid & 1;
        int eo   = wid >> 1;
        int e = eo / DOUT, o = eo % DOUT;

        const float4* wr = (const float4*)(W + ((size_t)e * DOUT + o) * DIN);
        float4 w4[3];
        #pragma unroll
        for (int k = 0; k < 3; ++k) w4[k] = wr[lane + 64 * k];

        if (half == 0) {
            ushort4* wo = (ushort4*)(wb + ((size_t)e * DOUT + o) * DIN);
            #pragma unroll
            for (int k = 0; k < 3; ++k) {
                ushort4 u;
                u.x = f2bf(w4[k].x); u.y = f2bf(w4[k].y);
                u.z = f2bf(w4[k].z); u.w = f2bf(w4[k].w);
                wo[lane + 64 * k] = u;
            }
        }

        int l0 = 25 * half;
        for (int l = l0; l < l0 + 25; ++l) {
            const float4* br = (const float4*)(bias + ((size_t)e * LSEQ + l) * DIN);
            float acc = 0.0f;
            #pragma unroll
            for (int k = 0; k < 3; ++k) {
                float4 b = br[lane + 64 * k];
                acc += b.x * w4[k].x + b.y * w4[k].y + b.z * w4[k].z + b.w * w4[k].w;
            }
            #pragma unroll
            for (int m = 32; m > 0; m >>= 1) acc += __shfl_xor(acc, m, 64);
            if (lane == 0) bw[((size_t)l * NEXP + e) * DOUT + o] = acc;
        }
    }
}

// ---------------------------------------------------------------------------
// Kernel 2 (ROUND 13): A-direct + REGISTER double-buffer.
// R7 post-mortem: A-direct removed the DS round-trip (conflicts 8.76M->5.84M,
// exactly as modeled) yet regressed 120->149 us because A became a SAME-
// ITERATION VGPR load: issued at iter top, consumed ~200 cyc later behind
// vmcnt -> exposed L2 latency every iteration (old GLDS16 staged A a full
// iteration ahead). Fix: software-pipeline A in registers — load A_{j+1}
// into a second NAMED set (aN*) during iter j (rule #20: static names, x2
// unrolled loop, no runtime-indexed arrays). A now ages a full iteration
// (~1600+ cyc) before use; the compiler's exact per-register waitcnt handles
// its completion. B keeps the proven GLDS16 double-buffer + counted vmcnt.
// vmcnt ledger/wave: top of iter j issues A_{j+1}(4 newest) -> vmcnt(4)
// waits B_j(2, staged iter j-1) + all older; barrier; stage B_{j+1}(2);
// ds_read B_j + lgkmcnt(0); MFMA on A_j. Tail: vmcnt(0).
// Regs: +16 VGPR (aN set) -> ~120 arch + 128 acc = 248 <= 256 (R5 precedent),
// keeps 2 blocks/CU. Geometry/epilogue/grid byte-identical to R7.
// ---------------------------------------------------------------------------
#define GTM 256            // tokens per block
#define GTO 16             // outputs per block (x 8 experts = 128 cols)
#define GKIT (DIN / 32)    // 24 K-tiles
#define NRT  (NTOK / GTM)  // 100 row tiles
#define NOT  19            // o tiles
#define RPG  13            // row-tiles per XCD group (8*13=104 >= 100)
#define NSLOT (8 * RPG * NOT)   // 1976
#define BBUF 8192          // one B buffer (128 rows x 64 B)

#define MFMA32(A0, A1, A2, A3)                                                      \
    acc[0][0] = __builtin_amdgcn_mfma_f32_16x16x32_bf16(A0, b0, acc[0][0], 0, 0, 0); \
    acc[0][1] = __builtin_amdgcn_mfma_f32_16x16x32_bf16(A0, b1, acc[0][1], 0, 0, 0); \
    acc[0][2] = __builtin_amdgcn_mfma_f32_16x16x32_bf16(A0, b2, acc[0][2], 0, 0, 0); \
    acc[0][3] = __builtin_amdgcn_mfma_f32_16x16x32_bf16(A0, b3, acc[0][3], 0, 0, 0); \
    acc[0][4] = __builtin_amdgcn_mfma_f32_16x16x32_bf16(A0, b4, acc[0][4], 0, 0, 0); \
    acc[0][5] = __builtin_amdgcn_mfma_f32_16x16x32_bf16(A0, b5, acc[0][5], 0, 0, 0); \
    acc[0][6] = __builtin_amdgcn_mfma_f32_16x16x32_bf16(A0, b6, acc[0][6], 0, 0, 0); \
    acc[0][7] = __builtin_amdgcn_mfma_f32_16x16x32_bf16(A0, b7, acc[0][7], 0, 0, 0); \
    acc[1][0] = __builtin_amdgcn_mfma_f32_16x16x32_bf16(A1, b0, acc[1][0], 0, 0, 0); \
    acc[1][1] = __builtin_amdgcn_mfma_f32_16x16x32_bf16(A1, b1, acc[1][1], 0, 0, 0); \
    acc[1][2] = __builtin_amdgcn_mfma_f32_16x16x32_bf16(A1, b2, acc[1][2], 0, 0, 0); \
    acc[1][3] = __builtin_amdgcn_mfma_f32_16x16x32_bf16(A1, b3, acc[1][3], 0, 0, 0); \
    acc[1][4] = __builtin_amdgcn_mfma_f32_16x16x32_bf16(A1, b4, acc[1][4], 0, 0, 0); \
    acc[1][5] = __builtin_amdgcn_mfma_f32_16x16x32_bf16(A1, b5, acc[1][5], 0, 0, 0); \
    acc[1][6] = __builtin_amdgcn_mfma_f32_16x16x32_bf16(A1, b6, acc[1][6], 0, 0, 0); \
    acc[1][7] = __builtin_amdgcn_mfma_f32_16x16x32_bf16(A1, b7, acc[1][7], 0, 0, 0); \
    acc[2][0] = __builtin_amdgcn_mfma_f32_16x16x32_bf16(A2, b0, acc[2][0], 0, 0, 0); \
    acc[2][1] = __builtin_amdgcn_mfma_f32_16x16x32_bf16(A2, b1, acc[2][1], 0, 0, 0); \
    acc[2][2] = __builtin_amdgcn_mfma_f32_16x16x32_bf16(A2, b2, acc[2][2], 0, 0, 0); \
    acc[2][3] = __builtin_amdgcn_mfma_f32_16x16x32_bf16(A2, b3, acc[2][3], 0, 0, 0); \
    acc[2][4] = __builtin_amdgcn_mfma_f32_16x16x32_bf16(A2, b4, acc[2][4], 0, 0, 0); \
    acc[2][5] = __builtin_amdgcn_mfma_f32_16x16x32_bf16(A2, b5, acc[2][5], 0, 0, 0); \
    acc[2][6] = __builtin_amdgcn_mfma_f32_16x16x32_bf16(A2, b6, acc[2][6], 0, 0, 0); \
    acc[2][7] = __builtin_amdgcn_mfma_f32_16x16x32_bf16(A2, b7, acc[2][7], 0, 0, 0); \
    acc[3][0] = __builtin_amdgcn_mfma_f32_16x16x32_bf16(A3, b0, acc[3][0], 0, 0, 0); \
    acc[3][1] = __builtin_amdgcn_mfma_f32_16x16x32_bf16(A3, b1, acc[3][1], 0, 0, 0); \
    acc[3][2] = __builtin_amdgcn_mfma_f32_16x16x32_bf16(A3, b2, acc[3][2], 0, 0, 0); \
    acc[3][3] = __builtin_amdgcn_mfma_f32_16x16x32_bf16(A3, b3, acc[3][3], 0, 0, 0); \
    acc[3][4] = __builtin_amdgcn_mfma_f32_16x16x32_bf16(A3, b4, acc[3][4], 0, 0, 0); \
    acc[3][5] = __builtin_amdgcn_mfma_f32_16x16x32_bf16(A3, b5, acc[3][5], 0, 0, 0); \
    acc[3][6] = __builtin_amdgcn_mfma_f32_16x16x32_bf16(A3, b6, acc[3][6], 0, 0, 0); \
    acc[3][7] = __builtin_amdgcn_mfma_f32_16x16x32_bf16(A3, b7, acc[3][7], 0, 0, 0);

// One K-iteration. AU* = A regs for THIS tile (loaded last iter);
// AL* = A regs for NEXT tile (loaded here, used next iter).
#define KBODY(J, AU0, AU1, AU2, AU3, AL0, AL1, AL2, AL3) do {                  \
    const int jj  = (J);                                                       \
    const int cur = jj & 1;                                                    \
    if (jj + 1 < GKIT) {                                                       \
        AL0 = *(const bf16x8*)(xga[0]);                                        \
        AL1 = *(const bf16x8*)(xga[1]);                                        \
        AL2 = *(const bf16x8*)(xga[2]);                                        \
        AL3 = *(const bf16x8*)(xga[3]);                                        \
        xga[0] += 64; xga[1] += 64; xga[2] += 64; xga[3] += 64;                \
        asm volatile("s_waitcnt vmcnt(4)" ::: "memory");  /* B_j done */       \
    } else {                                                                   \
        asm volatile("s_waitcnt vmcnt(0)" ::: "memory");  /* tail drain */     \
    }                                                                          \
    __builtin_amdgcn_s_barrier();            /* B_j visible; prev readers done */ \
    __builtin_amdgcn_sched_barrier(0);                                         \
    if (jj + 1 < GKIT) {                                                       \
        char* nb = lds + BBUF * (cur ^ 1);                                     \
        GLDS16(wq[0], nb + 2048 * w);                                          \
        GLDS16(wq[1], nb + 2048 * w + 1024);                                   \
        wq[0] += 64; wq[1] += 64;                                              \
    }                                                                          \
    const char* cb = lds + BBUF * cur;                                         \
    bf16x8 b0 = *(const bf16x8*)(cb + boff[0]);                                \
    bf16x8 b1 = *(const bf16x8*)(cb + boff[1]);                                \
    bf16x8 b2 = *(const bf16x8*)(cb + boff[2]);                                \
    bf16x8 b3 = *(const bf16x8*)(cb + boff[3]);                                \
    bf16x8 b4 = *(const bf16x8*)(cb + boff[4]);                                \
    bf16x8 b5 = *(const bf16x8*)(cb + boff[5]);                                \
    bf16x8 b6 = *(const bf16x8*)(cb + boff[6]);                                \
    bf16x8 b7 = *(const bf16x8*)(cb + boff[7]);                                \
    asm volatile("s_waitcnt lgkmcnt(0)" ::: "memory");                         \
    __builtin_amdgcn_sched_barrier(0);                                         \
    MFMA32(AU0, AU1, AU2, AU3)                                                 \
} while (0)

__global__ __launch_bounds__(256, 2) void moe_mfma_kernel(
    const bf16_t* __restrict__ xb, const bf16_t* __restrict__ wb,
    const float* __restrict__ gates, const float* __restrict__ bw,
    float* __restrict__ out)
{
    // grid decode: bid = slot*8 + g; slot = r_in*19 + o_t; r_t = g*13 + r_in
    const int bid  = blockIdx.x;
    const int g    = bid & 7;
    const int slot = bid >> 3;
    const int r_in = slot / NOT;
    const int o_t  = slot - NOT * r_in;
    const int r_t  = g * RPG + r_in;
    if (r_t >= NRT) return;            // uniform early-exit (before any barrier)
    const int o0 = o_t * GTO;
    const int t0 = r_t * GTM;

    __shared__ __align__(16) char lds[2 * BBUF];   // 16384 B: B double-buffer

    const int tid  = threadIdx.x;
    const int w    = tid >> 6;
    const int lane = tid & 63;

    // ---- B staging (swizzle scheme verified rounds 2-5) ----
    const int srow4 = lane >> 2;                          // 0..15
    const int c16   = 16 * ((lane & 3) ^ ((lane >> 4) & 3));

    const char* wq[2];
    #pragma unroll
    for (int j = 0; j < 2; ++j) {
        int n = 32 * w + 16 * j + srow4;
        int e = n >> 4;
        int o = o0 + (n & 15); if (o >= DOUT) o = DOUT - 1;  // clamp; guarded at store
        wq[j] = (const char*)wb + (size_t)(e * DOUT + o) * (DIN * 2) + c16;
    }

    // ---- fragment addressing ----
    const int m = lane & 15, q = lane >> 4;
    const int sw = 16 * (q ^ ((m >> 2) & 3));
    int boff[8];
    #pragma unroll
    for (int cf = 0; cf < 8; ++cf) boff[cf] = (16 * cf + m) * 64 + sw;

    // A direct-from-global: lane (m,q) of frag rf reads 16 B at
    // row = t0 + 64w + 16rf + m, byte = row*1536 + k0 + q*16.
    const char* xga[4];
    #pragma unroll
    for (int rf = 0; rf < 4; ++rf)
        xga[rf] = (const char*)xb + (size_t)(t0 + 64 * w + 16 * rf + m) * (DIN * 2) + q * 16;

    f32x4 acc[4][8] = {};

    // ---- prologue: stage B_0 (2 glds) and load A_0 into aC (4 vgpr loads) --
    GLDS16(wq[0], lds + 2048 * w);
    GLDS16(wq[1], lds + 2048 * w + 1024);
    wq[0] += 64; wq[1] += 64;

    bf16x8 aC0 = *(const bf16x8*)(xga[0]);
    bf16x8 aC1 = *(const bf16x8*)(xga[1]);
    bf16x8 aC2 = *(const bf16x8*)(xga[2]);
    bf16x8 aC3 = *(const bf16x8*)(xga[3]);
    xga[0] += 64; xga[1] += 64; xga[2] += 64; xga[3] += 64;
    bf16x8 aN0, aN1, aN2, aN3;

    for (int it = 0; it < GKIT; it += 2) {
        KBODY(it,     aC0, aC1, aC2, aC3, aN0, aN1, aN2, aN3);
        KBODY(it + 1, aN0, aN1, aN2, aN3, aC0, aC1, aC2, aC3);
    }

    // ---- epilogue: out[t,o] = sum_e g[t,e] * (acc - bw[l,e,o]) (VERBATIM) --
    const int o = o0 + m;
    if (o < DOUT) {
        #pragma unroll
        for (int rf = 0; rf < 4; ++rf) {
            #pragma unroll
            for (int r = 0; r < 4; ++r) {
                int t = t0 + 64 * w + 16 * rf + 4 * q + r;
                int l = t % LSEQ;
                float4 g0 = *(const float4*)(gates + (size_t)t * NEXP);
                float4 g1 = *(const float4*)(gates + (size_t)t * NEXP + 4);
                const float* bp = bw + (size_t)l * NEXP * DOUT + o;
                float s = 0.0f;
                s += g0.x * (acc[rf][0][r] - bp[0 * DOUT]);
                s += g0.y * (acc[rf][1][r] - bp[1 * DOUT]);
                s += g0.z * (acc[rf][2][r] - bp[2 * DOUT]);
                s += g0.w * (acc[rf][3][r] - bp[3 * DOUT]);
                s += g1.x * (acc[rf][4][r] - bp[4 * DOUT]);
                s += g1.y * (acc[rf][5][r] - bp[5 * DOUT]);
                s += g1.z * (acc[rf][6][r] - bp[6 * DOUT]);
                s += g1.w * (acc[rf][7][r] - bp[7 * DOUT]);
                out[(size_t)t * DOUT + o] = s;
            }
        }
    }
}

// ---------------------------------------------------------------------------
// Fallback fp32 path (verified round 1) — only if ws too small for bf16 bufs.
// ---------------------------------------------------------------------------
__global__ __launch_bounds__(256) void gates_kernel(
    const float* __restrict__ x, const float* __restrict__ wg,
    float* __restrict__ gates)
{
    int t    = blockIdx.x * 4 + (threadIdx.x >> 6);
    int lane = threadIdx.x & 63;
    const float* xr = x + (size_t)t * DIN;
    float acc[NEXP];
    #pragma unroll
    for (int e = 0; e < NEXP; e++) acc[e] = 0.0f;
    for (int i = lane; i < DIN; i += 64) {
        float xv = xr[i];
        const float* wr = wg + (size_t)i * NEXP;
        #pragma unroll
        for (int e = 0; e < NEXP; e++) acc[e] += xv * wr[e];
    }
    #pragma unroll
    for (int e = 0; e < NEXP; e++) {
        #pragma unroll
        for (int m = 32; m > 0; m >>= 1) acc[e] += __shfl_xor(acc[e], m, 64);
    }
    float mx = acc[0];
    #pragma unroll
    for (int e = 1; e < NEXP; e++) mx = fmaxf(mx, acc[e]);
    float ex[NEXP]; float s = 0.0f;
    #pragma unroll
    for (int e = 0; e < NEXP; e++) { ex[e] = __expf(acc[e] - mx); s += ex[e]; }
    float inv = 1.0f / s;
    if (lane == 0) {
        #pragma unroll
        for (int e = 0; e < NEXP; e++) gates[(size_t)t * NEXP + e] = ex[e] * inv;
    }
}

__global__ __launch_bounds__(256) void bw_kernel(
    const float* __restrict__ bias, const float* __restrict__ W,
    float* __restrict__ bw)
{
    int wave = blockIdx.x * 4 + (threadIdx.x >> 6);
    int lane = threadIdx.x & 63;
    int l   = wave / (NEXP * DOUT);
    int rem = wave % (NEXP * DOUT);
    int e   = rem / DOUT;
    int o   = rem % DOUT;
    const float4* br = (const float4*)(bias + ((size_t)e * LSEQ + l) * DIN);
    const float4* wr = (const float4*)(W    + ((size_t)e * DOUT + o) * DIN);
    float acc = 0.0f;
    #pragma unroll
    for (int k = 0; k < 3; ++k) {
        int i4 = lane + 64 * k;
        float4 b = br[i4], w = wr[i4];
        acc += b.x * w.x + b.y * w.y + b.z * w.z + b.w * w.w;
    }
    #pragma unroll
    for (int m = 32; m > 0; m >>= 1) acc += __shfl_xor(acc, m, 64);
    if (lane == 0) bw[((size_t)l * NEXP + e) * DOUT + o] = acc;
}

#define TM  64
#define TO  16
#define KT  32
#define KTP 36

__global__ __launch_bounds__(256) void moe_main_kernel(
    const float* __restrict__ x, const float* __restrict__ W,
    const float* __restrict__ gates, const float* __restrict__ bw,
    float* __restrict__ out)
{
    __shared__ float Xs[TM][KTP];
    __shared__ float Wls[128][KTP];
    const int tid = threadIdx.x;
    const int t0 = blockIdx.x * TM;
    const int o0 = blockIdx.y * TO;
    const int cg = tid & 15;
    const int tg = tid >> 4;
    const int lrow = tid >> 3;
    const int lk4  = (tid & 7) * 4;
    float acc[4][NEXP];
    #pragma unroll
    for (int i = 0; i < 4; i++)
        #pragma unroll
        for (int j = 0; j < NEXP; j++) acc[i][j] = 0.0f;
    for (int k0 = 0; k0 < DIN; k0 += KT) {
        #pragma unroll
        for (int r = 0; r < 2; r++) {
            int row = lrow + 32 * r;
            float4 v = *(const float4*)&x[((size_t)(t0 + row)) * DIN + k0 + lk4];
            *(float4*)&Xs[row][lk4] = v;
        }
        #pragma unroll
        for (int r = 0; r < 4; r++) {
            int nl = lrow + 32 * r;
            int e  = nl >> 4;
            int o  = o0 + (nl & 15);
            float4 v;
            if (o < DOUT)
                v = *(const float4*)&W[((size_t)e * DOUT + o) * DIN + k0 + lk4];
            else
                v = make_float4(0.f, 0.f, 0.f, 0.f);
            *(float4*)&Wls[nl][lk4] = v;
        }
        __syncthreads();
        #pragma unroll
        for (int k4 = 0; k4 < KT; k4 += 4) {
            float4 xa[4], wb4[NEXP];
            #pragma unroll
            for (int i = 0; i < 4; i++)
                xa[i] = *(const float4*)&Xs[tg + 16 * i][k4];
            #pragma unroll
            for (int j = 0; j < NEXP; j++)
                wb4[j] = *(const float4*)&Wls[cg + 16 * j][k4];
            #pragma unroll
            for (int i = 0; i < 4; i++)
                #pragma unroll
                for (int j = 0; j < NEXP; j++) {
                    acc[i][j] += xa[i].x * wb4[j].x;
                    acc[i][j] += xa[i].y * wb4[j].y;
                    acc[i][j] += xa[i].z * wb4[j].z;
                    acc[i][j] += xa[i].w * wb4[j].w;
                }
        }
        __syncthreads();
    }
    const int o = o0 + cg;
    if (o < DOUT) {
        #pragma unroll
        for (int i = 0; i < 4; i++) {
            int t = t0 + tg + 16 * i;
            int l = t % LSEQ;
            float s = 0.0f;
            #pragma unroll
            for (int j = 0; j < NEXP; j++) {
                float g = gates[(size_t)t * NEXP + j];
                s += g * (acc[i][j] - bw[((size_t)l * NEXP + j) * DOUT + o]);
            }
            out[(size_t)t * DOUT + o] = s;
        }
    }
}

// ---------------------------------------------------------------------------
extern "C" void kernel_launch(void* const* d_in, const int* in_sizes, int n_in,
                              void* d_out, int out_size, void* d_ws, size_t ws_size,
                              hipStream_t stream) {
    const float* x     = (const float*)d_in[0];   // [512,50,768]
    const float* wgate = (const float*)d_in[1];   // [768,8]
    const float* ew    = (const float*)d_in[2];   // [8,300,768]
    const float* ebias = (const float*)d_in[3];   // [8,50,768]
    float* out = (float*)d_out;                   // [512,50,300]

    // ws layout: gates | bw | xb (bf16) | wb (bf16)
    const size_t n_gates = (size_t)NTOK * NEXP;           // 204800 f32
    const size_t n_bw    = (size_t)LSEQ * NEXP * DOUT;    // 120000 f32
    const size_t n_x     = (size_t)NTOK * DIN;            // 19,660,800
    const size_t n_w     = (size_t)NEXP * DOUT * DIN;     // 1,843,200

    float* gates = (float*)d_ws;
    float* bw    = gates + n_gates;
    bf16_t* xb   = (bf16_t*)(bw + n_bw);
    bf16_t* wbuf = xb + n_x;

    const size_t need = (n_gates + n_bw) * 4 + (n_x + n_w) * 2;

    if (ws_size >= need) {
        prep_kernel<<<PREP_GATE_BLOCKS + PREP_BW_BLOCKS, 256, 0, stream>>>(
            x, wgate, ebias, ew, (unsigned short*)xb, gates, bw, (unsigned short*)wbuf);
        moe_mfma_kernel<<<NSLOT, 256, 0, stream>>>(xb, wbuf, gates, bw, out);
    } else {
        gates_kernel<<<NTOK / 4, 256, 0, stream>>>(x, wgate, gates);
        bw_kernel<<<(LSEQ * NEXP * DOUT) / 4, 256, 0, stream>>>(ebias, ew, bw);
        dim3 grid(NTOK / TM, (DOUT + TO - 1) / TO);      // 400 x 19
        moe_main_kernel<<<grid, 256, 0, stream>>>(x, ew, gates, bw, out);
    }
}

// Round 10
// 256.541 us; speedup vs baseline: 1.1128x; 1.1128x over previous
//
#include <hip/hip_runtime.h>
#include <hip/hip_bf16.h>

// Problem constants (MoEAdaptorLayer_111669150283)
#define BATCH   512
#define LSEQ    50
#define DIN     768
#define DOUT    300
#define NEXP    8
#define NTOK    (BATCH * LSEQ)      // 25600

typedef __bf16 bf16_t;
typedef __attribute__((ext_vector_type(8))) __bf16 bf16x8;
typedef __attribute__((ext_vector_type(4))) float f32x4;

// async global->LDS, 16 B per lane, dst = wave-uniform base + lane*16
#define GLDS16(g, l) __builtin_amdgcn_global_load_lds( \
    (__attribute__((address_space(1))) void*)(g), \
    (__attribute__((address_space(3))) void*)(l), 16, 0, 0)

static __device__ __forceinline__ unsigned short f2bf(float f) {
    unsigned u = __float_as_uint(f);
    u = (u + 0x7fff + ((u >> 16) & 1)) >> 16;   // round-to-nearest-even
    return (unsigned short)u;
}

// ---------------------------------------------------------------------------
// Kernel 1 (merged prep): block-range split. VERBATIM R0 (verified, ~33 us).
//   blocks [0, 6400):    xb = bf16(x), gates = softmax(x @ w_gate)
//   blocks [6400, 7600): bw[l,e,o] = <bias[e,l,:], W[e,o,:]>, wb = bf16(W)
// ---------------------------------------------------------------------------
#define PREP_GATE_BLOCKS (NTOK / 4)              // 6400
#define PREP_BW_BLOCKS   ((2 * NEXP * DOUT) / 4) // 1200

__global__ __launch_bounds__(256) void prep_kernel(
    const float* __restrict__ x, const float* __restrict__ wg,
    const float* __restrict__ bias, const float* __restrict__ W,
    unsigned short* __restrict__ xb, float* __restrict__ gates,
    float* __restrict__ bw, unsigned short* __restrict__ wb)
{
    const int tid  = threadIdx.x;
    const int lane = tid & 63;

    if (blockIdx.x < PREP_GATE_BLOCKS) {
        __shared__ float wgT[NEXP][DIN + 4];   // transposed gate weights
        #pragma unroll
        for (int r = 0; r < 6; ++r) {
            int j = tid + 256 * r;             // float4 index 0..1535
            float4 v = ((const float4*)wg)[j];
            int i  = j >> 1;
            int e0 = (j & 1) * 4;
            wgT[e0 + 0][i] = v.x;
            wgT[e0 + 1][i] = v.y;
            wgT[e0 + 2][i] = v.z;
            wgT[e0 + 3][i] = v.w;
        }
        __syncthreads();

        int t = blockIdx.x * 4 + (tid >> 6);
        const float4* xr = (const float4*)(x + (size_t)t * DIN);
        ushort4* xo = (ushort4*)(xb + (size_t)t * DIN);

        float acc[NEXP];
        #pragma unroll
        for (int e = 0; e < NEXP; e++) acc[e] = 0.0f;

        #pragma unroll
        for (int k = 0; k < 3; ++k) {
            int i4 = lane + 64 * k;
            float4 v = xr[i4];
            ushort4 u;
            u.x = f2bf(v.x); u.y = f2bf(v.y); u.z = f2bf(v.z); u.w = f2bf(v.w);
            xo[i4] = u;
            #pragma unroll
            for (int e = 0; e < NEXP; ++e) {
                float4 wv = *(const float4*)&wgT[e][4 * i4];
                acc[e] += v.x * wv.x + v.y * wv.y + v.z * wv.z + v.w * wv.w;
            }
        }
        #pragma unroll
        for (int e = 0; e < NEXP; e++) {
            #pragma unroll
            for (int m = 32; m > 0; m >>= 1) acc[e] += __shfl_xor(acc[e], m, 64);
        }
        float mx = acc[0];
        #pragma unroll
        for (int e = 1; e < NEXP; e++) mx = fmaxf(mx, acc[e]);
        float ex[NEXP]; float s = 0.0f;
        #pragma unroll
        for (int e = 0; e < NEXP; e++) { ex[e] = __expf(acc[e] - mx); s += ex[e]; }
        float inv = 1.0f / s;
        if (lane == 0) {
            #pragma unroll
            for (int e = 0; e < NEXP; e++) gates[(size_t)t * NEXP + e] = ex[e] * inv;
        }
    } else {
        int wid  = (blockIdx.x - PREP_GATE_BLOCKS) * 4 + (tid >> 6);  // 0..4799
        int half = wid & 1;
        int eo   = wid >> 1;
        int e = eo / DOUT, o = eo % DOUT;

        const float4* wr = (const float4*)(W + ((size_t)e * DOUT + o) * DIN);
        float4 w4[3];
        #pragma unroll
        for (int k = 0; k < 3; ++k) w4[k] = wr[lane + 64 * k];

        if (half == 0) {
            ushort4* wo = (ushort4*)(wb + ((size_t)e * DOUT + o) * DIN);
            #pragma unroll
            for (int k = 0; k < 3; ++k) {
                ushort4 u;
                u.x = f2bf(w4[k].x); u.y = f2bf(w4[k].y);
                u.z = f2bf(w4[k].z); u.w = f2bf(w4[k].w);
                wo[lane + 64 * k] = u;
            }
        }

        int l0 = 25 * half;
        for (int l = l0; l < l0 + 25; ++l) {
            const float4* br = (const float4*)(bias + ((size_t)e * LSEQ + l) * DIN);
            float acc = 0.0f;
            #pragma unroll
            for (int k = 0; k < 3; ++k) {
                float4 b = br[lane + 64 * k];
                acc += b.x * w4[k].x + b.y * w4[k].y + b.z * w4[k].z + b.w * w4[k].w;
            }
            #pragma unroll
            for (int m = 32; m > 0; m >>= 1) acc += __shfl_xor(acc, m, 64);
            if (lane == 0) bw[((size_t)l * NEXP + e) * DOUT + o] = acc;
        }
    }
}

// ---------------------------------------------------------------------------
// Kernel 2 (R5 RESTORED VERBATIM, banked best: 120 us GEMM / 257 us total).
// Resubmitted unchanged after round-9 infra failure (container failed twice;
// no counters produced — same source passed and benched in R5).
// Exploration record: R6 8-wave phasing -40% (1 block/CU barrier exposure);
// R7/R8 A-direct -24/-27% (MFMA fragment m-major scatter defeats L2
// coalescing; A's LDS round-trip pays for the staging-order -> fragment-
// order transform and is NOT removable overhead). R5's 2-barrier counted-
// vmcnt loop at 2 blocks/CU is the verified local optimum; the only
// unexplored structural move is a ground-up m201 256x256 template port.
//   wave tile 80x128 (rf5 x cf8), block 320x128, acc[5][8]=160 regs;
//   dbuf LDS 2x28KB; vmcnt(7) counted wait; XCD-exact grid 8x10x19.
// ---------------------------------------------------------------------------
#define GTM 320            // tokens per block (25600/320 = 80 exact)
#define GTO 16             // outputs per block (x 8 experts = 128 cols)
#define GBK 32             // k per iteration
#define GKIT (DIN / GBK)   // 24
#define NRT  (NTOK / GTM)  // 80 row tiles
#define NOT  19            // o tiles
#define RPG  10            // row-tiles per XCD group (8*10 = 80 exact)
#define NSLOT (8 * RPG * NOT)   // 1520

#define XBYTES 20480       // 320 rows x 64 B
#define BUFB   28672       // Xs 20K | Ws 8K

__global__ __launch_bounds__(256, 2) void moe_mfma_kernel(
    const bf16_t* __restrict__ xb, const bf16_t* __restrict__ wb,
    const float* __restrict__ gates, const float* __restrict__ bw,
    float* __restrict__ out)
{
    // grid decode: bid = slot*8 + g; slot = r_in*19 + o_t; r_t = g*10 + r_in
    const int bid  = blockIdx.x;
    const int g    = bid & 7;
    const int slot = bid >> 3;
    const int r_in = slot / NOT;           // 0..9
    const int o_t  = slot - NOT * r_in;    // 0..18
    const int r_t  = g * RPG + r_in;       // 0..79, always valid
    const int o0 = o_t * GTO;
    const int t0 = r_t * GTM;

    __shared__ __align__(16) char lds[2 * BUFB];   // 57344 B, double-buffered

    const int tid  = threadIdx.x;
    const int w    = tid >> 6;
    const int lane = tid & 63;

    // ---- staging (swizzle scheme verified rounds 2-5) ----
    const int srow4 = lane >> 2;                          // 0..15
    const int c16   = 16 * ((lane & 3) ^ ((lane >> 4) & 3));

    // X: 5 GLDS16/wave covering rows 16*(5w+j)+srow4, j=0..4 (rows 0..319)
    const char* xg[5];
    #pragma unroll
    for (int j = 0; j < 5; ++j)
        xg[j] = (const char*)xb + (size_t)(t0 + 16 * (5 * w + j) + srow4) * (DIN * 2) + c16;

    // W: 2 GLDS16/wave, rows n = 32w+16j+srow4 (0..127), e = n>>4, o = o0+(n&15)
    const char* wq[2];
    #pragma unroll
    for (int j = 0; j < 2; ++j) {
        int n = 32 * w + 16 * j + srow4;
        int e = n >> 4;
        int o = o0 + (n & 15); if (o >= DOUT) o = DOUT - 1;  // clamp; guarded at store
        wq[j] = (const char*)wb + (size_t)(e * DOUT + o) * (DIN * 2) + c16;
    }

    // ---- fragment read offsets (swizzled), relative to buffer base ----
    const int m = lane & 15, q = lane >> 4;
    const int sw = 16 * (q ^ ((m >> 2) & 3));
    int aoff[5], boff[8];
    #pragma unroll
    for (int rf = 0; rf < 5; ++rf) aoff[rf] = 64 * (80 * w + 16 * rf + m) + sw;
    #pragma unroll
    for (int cf = 0; cf < 8; ++cf) boff[cf] = XBYTES + 64 * (16 * cf + m) + sw;

    f32x4 acc[5][8] = {};

    // ---- prologue: stage K-tile 0 into buffer 0 (no wait here) ----
    {
        char* xl = lds + 1024 * (5 * w);
        char* wl = lds + XBYTES + 2048 * w;
        #pragma unroll
        for (int j = 0; j < 5; ++j) { GLDS16(xg[j], xl + 1024 * j); xg[j] += 64; }
        #pragma unroll
        for (int j = 0; j < 2; ++j) { GLDS16(wq[j], wl + 1024 * j); wq[j] += 64; }
    }

    for (int it = 0; it < GKIT; ++it) {
        const int cur = it & 1;
        // ---- issue next tile's loads, then wait ONLY for current tile ----
        if (it + 1 < GKIT) {
            char* nb = lds + BUFB * (cur ^ 1);
            char* xl = nb + 1024 * (5 * w);
            char* wl = nb + XBYTES + 2048 * w;
            #pragma unroll
            for (int j = 0; j < 5; ++j) { GLDS16(xg[j], xl + 1024 * j); xg[j] += 64; }
            #pragma unroll
            for (int j = 0; j < 2; ++j) { GLDS16(wq[j], wl + 1024 * j); wq[j] += 64; }
            asm volatile("s_waitcnt vmcnt(7)" ::: "memory");   // cur-tile loads done
        } else {
            asm volatile("s_waitcnt vmcnt(0)" ::: "memory");   // tail: drain all
        }
        __builtin_amdgcn_s_barrier();          // cur-tile data block-visible
        __builtin_amdgcn_sched_barrier(0);

        const char* cb = lds + BUFB * cur;
        bf16x8 a[5];
        #pragma unroll
        for (int rf = 0; rf < 5; ++rf) a[rf] = *(const bf16x8*)(cb + aoff[rf]);
        #pragma unroll
        for (int cf = 0; cf < 8; ++cf) {
            bf16x8 b = *(const bf16x8*)(cb + boff[cf]);
            #pragma unroll
            for (int rf = 0; rf < 5; ++rf)
                acc[rf][cf] = __builtin_amdgcn_mfma_f32_16x16x32_bf16(a[rf], b, acc[rf][cf], 0, 0, 0);
        }

        // pin all ds_reads complete (rule #18), then barrier WITHOUT vmcnt
        // drain — next-tile loads stay in flight across it (T4).
        __builtin_amdgcn_sched_barrier(0);
        asm volatile("s_waitcnt lgkmcnt(0)" ::: "memory");
        __builtin_amdgcn_sched_barrier(0);
        __builtin_amdgcn_s_barrier();          // readers done; overwrite safe
    }

    // ---- epilogue: out[t,o] = sum_e g[t,e] * (acc - bw[l,e,o]) ----
    const int o = o0 + m;
    if (o < DOUT) {
        #pragma unroll
        for (int rf = 0; rf < 5; ++rf) {
            #pragma unroll
            for (int r = 0; r < 4; ++r) {
                int t = t0 + 80 * w + 16 * rf + 4 * q + r;
                int l = t % LSEQ;
                float4 g0 = *(const float4*)(gates + (size_t)t * NEXP);
                float4 g1 = *(const float4*)(gates + (size_t)t * NEXP + 4);
                const float* bp = bw + (size_t)l * NEXP * DOUT + o;
                float s = 0.0f;
                s += g0.x * (acc[rf][0][r] - bp[0 * DOUT]);
                s += g0.y * (acc[rf][1][r] - bp[1 * DOUT]);
                s += g0.z * (acc[rf][2][r] - bp[2 * DOUT]);
                s += g0.w * (acc[rf][3][r] - bp[3 * DOUT]);
                s += g1.x * (acc[rf][4][r] - bp[4 * DOUT]);
                s += g1.y * (acc[rf][5][r] - bp[5 * DOUT]);
                s += g1.z * (acc[rf][6][r] - bp[6 * DOUT]);
                s += g1.w * (acc[rf][7][r] - bp[7 * DOUT]);
                out[(size_t)t * DOUT + o] = s;
            }
        }
    }
}

// ---------------------------------------------------------------------------
// Fallback fp32 path (verified round 1) — only if ws too small for bf16 bufs.
// ---------------------------------------------------------------------------
__global__ __launch_bounds__(256) void gates_kernel(
    const float* __restrict__ x, const float* __restrict__ wg,
    float* __restrict__ gates)
{
    int t    = blockIdx.x * 4 + (threadIdx.x >> 6);
    int lane = threadIdx.x & 63;
    const float* xr = x + (size_t)t * DIN;
    float acc[NEXP];
    #pragma unroll
    for (int e = 0; e < NEXP; e++) acc[e] = 0.0f;
    for (int i = lane; i < DIN; i += 64) {
        float xv = xr[i];
        const float* wr = wg + (size_t)i * NEXP;
        #pragma unroll
        for (int e = 0; e < NEXP; e++) acc[e] += xv * wr[e];
    }
    #pragma unroll
    for (int e = 0; e < NEXP; e++) {
        #pragma unroll
        for (int m = 32; m > 0; m >>= 1) acc[e] += __shfl_xor(acc[e], m, 64);
    }
    float mx = acc[0];
    #pragma unroll
    for (int e = 1; e < NEXP; e++) mx = fmaxf(mx, acc[e]);
    float ex[NEXP]; float s = 0.0f;
    #pragma unroll
    for (int e = 0; e < NEXP; e++) { ex[e] = __expf(acc[e] - mx); s += ex[e]; }
    float inv = 1.0f / s;
    if (lane == 0) {
        #pragma unroll
        for (int e = 0; e < NEXP; e++) gates[(size_t)t * NEXP + e] = ex[e] * inv;
    }
}

__global__ __launch_bounds__(256) void bw_kernel(
    const float* __restrict__ bias, const float* __restrict__ W,
    float* __restrict__ bw)
{
    int wave = blockIdx.x * 4 + (threadIdx.x >> 6);
    int lane = threadIdx.x & 63;
    int l   = wave / (NEXP * DOUT);
    int rem = wave % (NEXP * DOUT);
    int e   = rem / DOUT;
    int o   = rem % DOUT;
    const float4* br = (const float4*)(bias + ((size_t)e * LSEQ + l) * DIN);
    const float4* wr = (const float4*)(W    + ((size_t)e * DOUT + o) * DIN);
    float acc = 0.0f;
    #pragma unroll
    for (int k = 0; k < 3; ++k) {
        int i4 = lane + 64 * k;
        float4 b = br[i4], w = wr[i4];
        acc += b.x * w.x + b.y * w.y + b.z * w.z + b.w * w.w;
    }
    #pragma unroll
    for (int m = 32; m > 0; m >>= 1) acc += __shfl_xor(acc, m, 64);
    if (lane == 0) bw[((size_t)l * NEXP + e) * DOUT + o] = acc;
}

#define TM  64
#define TO  16
#define KT  32
#define KTP 36

__global__ __launch_bounds__(256) void moe_main_kernel(
    const float* __restrict__ x, const float* __restrict__ W,
    const float* __restrict__ gates, const float* __restrict__ bw,
    float* __restrict__ out)
{
    __shared__ float Xs[TM][KTP];
    __shared__ float Wls[128][KTP];
    const int tid = threadIdx.x;
    const int t0 = blockIdx.x * TM;
    const int o0 = blockIdx.y * TO;
    const int cg = tid & 15;
    const int tg = tid >> 4;
    const int lrow = tid >> 3;
    const int lk4  = (tid & 7) * 4;
    float acc[4][NEXP];
    #pragma unroll
    for (int i = 0; i < 4; i++)
        #pragma unroll
        for (int j = 0; j < NEXP; j++) acc[i][j] = 0.0f;
    for (int k0 = 0; k0 < DIN; k0 += KT) {
        #pragma unroll
        for (int r = 0; r < 2; r++) {
            int row = lrow + 32 * r;
            float4 v = *(const float4*)&x[((size_t)(t0 + row)) * DIN + k0 + lk4];
            *(float4*)&Xs[row][lk4] = v;
        }
        #pragma unroll
        for (int r = 0; r < 4; r++) {
            int nl = lrow + 32 * r;
            int e  = nl >> 4;
            int o  = o0 + (nl & 15);
            float4 v;
            if (o < DOUT)
                v = *(const float4*)&W[((size_t)e * DOUT + o) * DIN + k0 + lk4];
            else
                v = make_float4(0.f, 0.f, 0.f, 0.f);
            *(float4*)&Wls[nl][lk4] = v;
        }
        __syncthreads();
        #pragma unroll
        for (int k4 = 0; k4 < KT; k4 += 4) {
            float4 xa[4], wb4[NEXP];
            #pragma unroll
            for (int i = 0; i < 4; i++)
                xa[i] = *(const float4*)&Xs[tg + 16 * i][k4];
            #pragma unroll
            for (int j = 0; j < NEXP; j++)
                wb4[j] = *(const float4*)&Wls[cg + 16 * j][k4];
            #pragma unroll
            for (int i = 0; i < 4; i++)
                #pragma unroll
                for (int j = 0; j < NEXP; j++) {
                    acc[i][j] += xa[i].x * wb4[j].x;
                    acc[i][j] += xa[i].y * wb4[j].y;
                    acc[i][j] += xa[i].z * wb4[j].z;
                    acc[i][j] += xa[i].w * wb4[j].w;
                }
        }
        __syncthreads();
    }
    const int o = o0 + cg;
    if (o < DOUT) {
        #pragma unroll
        for (int i = 0; i < 4; i++) {
            int t = t0 + tg + 16 * i;
            int l = t % LSEQ;
            float s = 0.0f;
            #pragma unroll
            for (int j = 0; j < NEXP; j++) {
                float g = gates[(size_t)t * NEXP + j];
                s += g * (acc[i][j] - bw[((size_t)l * NEXP + j) * DOUT + o]);
            }
            out[(size_t)t * DOUT + o] = s;
        }
    }
}

// ---------------------------------------------------------------------------
extern "C" void kernel_launch(void* const* d_in, const int* in_sizes, int n_in,
                              void* d_out, int out_size, void* d_ws, size_t ws_size,
                              hipStream_t stream) {
    const float* x     = (const float*)d_in[0];   // [512,50,768]
    const float* wgate = (const float*)d_in[1];   // [768,8]
    const float* ew    = (const float*)d_in[2];   // [8,300,768]
    const float* ebias = (const float*)d_in[3];   // [8,50,768]
    float* out = (float*)d_out;                   // [512,50,300]

    // ws layout: gates | bw | xb (bf16) | wb (bf16)
    const size_t n_gates = (size_t)NTOK * NEXP;           // 204800 f32
    const size_t n_bw    = (size_t)LSEQ * NEXP * DOUT;    // 120000 f32
    const size_t n_x     = (size_t)NTOK * DIN;            // 19,660,800
    const size_t n_w     = (size_t)NEXP * DOUT * DIN;     // 1,843,200

    float* gates = (float*)d_ws;
    float* bw    = gates + n_gates;
    bf16_t* xb   = (bf16_t*)(bw + n_bw);
    bf16_t* wbuf = xb + n_x;

    const size_t need = (n_gates + n_bw) * 4 + (n_x + n_w) * 2;

    if (ws_size >= need) {
        prep_kernel<<<PREP_GATE_BLOCKS + PREP_BW_BLOCKS, 256, 0, stream>>>(
            x, wgate, ebias, ew, (unsigned short*)xb, gates, bw, (unsigned short*)wbuf);
        moe_mfma_kernel<<<NSLOT, 256, 0, stream>>>(xb, wbuf, gates, bw, out);
    } else {
        gates_kernel<<<NTOK / 4, 256, 0, stream>>>(x, wgate, gates);
        bw_kernel<<<(LSEQ * NEXP * DOUT) / 4, 256, 0, stream>>>(ebias, ew, bw);
        dim3 grid(NTOK / TM, (DOUT + TO - 1) / TO);      // 400 x 19
        moe_main_kernel<<<grid, 256, 0, stream>>>(x, ew, gates, bw, out);
    }
}